// Round 6
// baseline (1674.839 us; speedup 1.0000x reference)
//
#include <hip/hip_runtime.h>
#include <math.h>

#define TOK   1024
#define HSZ   1024
#define DIM   128
#define NWRDC 32000
#define NTGTC 2000

typedef __attribute__((ext_vector_type(8))) short bf16x8;
typedef __attribute__((ext_vector_type(4))) float f32x4;

__device__ __forceinline__ ushort f2bf(float x) {
    union { float f; uint u; } c; c.f = x;
    return (ushort)((c.u + 0x7fffu + ((c.u >> 16) & 1u)) >> 16);
}
__device__ __forceinline__ float bf2f(ushort h) {
    union { uint u; float f; } c; c.u = ((uint)h) << 16;
    return c.f;
}
__device__ __forceinline__ uint4 pk8(const ushort v[8]) {
    uint4 u;
    u.x = (uint)v[0] | ((uint)v[1] << 16);
    u.y = (uint)v[2] | ((uint)v[3] << 16);
    u.z = (uint)v[4] | ((uint)v[5] << 16);
    u.w = (uint)v[6] | ((uint)v[7] << 16);
    return u;
}
// sorted top-3 insert, ties -> smaller index wins
__device__ __forceinline__ void ins3(float v, int ix, float s[3], int ii[3]) {
    if (v > s[0] || (v == s[0] && ix < ii[0])) {
        s[2] = s[1]; ii[2] = ii[1]; s[1] = s[0]; ii[1] = ii[0]; s[0] = v; ii[0] = ix;
    } else if (v > s[1] || (v == s[1] && ix < ii[1])) {
        s[2] = s[1]; ii[2] = ii[1]; s[1] = v; ii[1] = ix;
    } else if (v > s[2] || (v == s[2] && ix < ii[2])) {
        s[2] = v; ii[2] = ix;
    }
}

#define GLL16(SRC, DST) __builtin_amdgcn_global_load_lds( \
    (const __attribute__((address_space(1))) void*)(SRC), \
    (__attribute__((address_space(3))) void*)(DST), 16, 0, 0)

// ---------------------------------------------------------------------------
// split ctx into 3 bf16 terms
// ---------------------------------------------------------------------------
__global__ __launch_bounds__(256) void split_ctx3(
    const float* __restrict__ x, ushort* __restrict__ hp,
    ushort* __restrict__ mp, ushort* __restrict__ lp)
{
    const int i4 = (blockIdx.x * 256 + threadIdx.x) * 4;
    float4 v = *(const float4*)(x + i4);
    float xs[4] = {v.x, v.y, v.z, v.w};
    ushort hh[4], mm[4], ll[4];
    #pragma unroll
    for (int k = 0; k < 4; ++k) {
        ushort h = f2bf(xs[k]);
        float r1 = xs[k] - bf2f(h);
        ushort m = f2bf(r1);
        ushort l = f2bf(r1 - bf2f(m));
        hh[k] = h; mm[k] = m; ll[k] = l;
    }
    uint2 u;
    u.x = (uint)hh[0] | ((uint)hh[1] << 16); u.y = (uint)hh[2] | ((uint)hh[3] << 16);
    *(uint2*)(hp + i4) = u;
    u.x = (uint)mm[0] | ((uint)mm[1] << 16); u.y = (uint)mm[2] | ((uint)mm[3] << 16);
    *(uint2*)(mp + i4) = u;
    u.x = (uint)ll[0] | ((uint)ll[1] << 16); u.y = (uint)ll[2] | ((uint)ll[3] << 16);
    *(uint2*)(lp + i4) = u;
}

// ---------------------------------------------------------------------------
// conv_wt: W [1024][V] f32 -> transposed Wh [Vpad][1024] bf16 (trunc-hi) and
// Wl residual (f32 if lf32, else bf16). Pad cols >= V are zeroed.
// grid (Vpad/256, 8), block 256; blockIdx.y covers 128 k-rows.
// ---------------------------------------------------------------------------
__global__ __launch_bounds__(256) void conv_wt(
    const float* __restrict__ W, int V,
    ushort* __restrict__ Wh, void* __restrict__ Wl, int lf32)
{
    const int col = blockIdx.x * 256 + threadIdx.x;
    const int k0 = blockIdx.y * 128;
    for (int kk = 0; kk < 128; kk += 8) {
        ushort h8[8], l8[8]; float lf[8];
        #pragma unroll
        for (int q = 0; q < 8; ++q) {
            float x = (col < V) ? W[(size_t)(k0 + kk + q) * V + col] : 0.f;
            union { float f; uint u; } c; c.f = x;
            ushort h = (ushort)(c.u >> 16);
            union { uint u; float f; } th; th.u = (uint)h << 16;
            float r = x - th.f;                 // exact f32 residual
            h8[q] = h; lf[q] = r; l8[q] = f2bf(r);
        }
        *(uint4*)(Wh + (size_t)col * 1024 + k0 + kk) = pk8(h8);
        if (lf32) {
            float* wl = (float*)Wl + (size_t)col * 1024 + k0 + kk;
            float4 a = {lf[0], lf[1], lf[2], lf[3]};
            float4 b = {lf[4], lf[5], lf[6], lf[7]};
            *(float4*)wl = a; *(float4*)(wl + 4) = b;
        } else {
            *(uint4*)((ushort*)Wl + (size_t)col * 1024 + k0 + kk) = pk8(l8);
        }
    }
}

// ---------------------------------------------------------------------------
// gemm_cpy: C = ctx @ W_cpy (3-term split, 6 passes) -- proven r2 code
// ---------------------------------------------------------------------------
__global__ __launch_bounds__(256, 2) void gemm_cpy(
    const ushort* __restrict__ ahi, const ushort* __restrict__ amd,
    const ushort* __restrict__ alo, const float* __restrict__ W,
    float* __restrict__ C)
{
    __shared__ __align__(16) ushort sm[30720];
    ushort* Ah = sm;
    ushort* Am = sm + 5120;
    ushort* Al = sm + 10240;
    ushort* Bh = sm + 15360;
    ushort* Bm = sm + 20480;
    ushort* Bl = sm + 25600;

    const int tid  = threadIdx.x;
    const int lane = tid & 63;
    const int fr   = lane & 15;
    const int fg   = lane >> 4;
    const int w    = tid >> 6;
    const int wrow = w >> 1;
    const int wcol = w & 1;
    const int t0   = blockIdx.x * 128;
    const int c0   = blockIdx.y * 128;

    const int arow = tid >> 2, akc = tid & 3;
    const int bcol = tid & 127, bkc0 = tid >> 7;

    f32x4 zero4 = {0.f, 0.f, 0.f, 0.f};
    f32x4 acc[4][4];
    #pragma unroll
    for (int i = 0; i < 4; ++i)
        #pragma unroll
        for (int j = 0; j < 4; ++j) acc[i][j] = zero4;

    for (int h0 = 0; h0 < HSZ; h0 += 32) {
        uint4 aH[2], aM[2], aL[2];
        float bx[2][8];
        #pragma unroll
        for (int rr = 0; rr < 2; ++rr) {
            const size_t so = (size_t)(t0 + arow + rr * 64) * HSZ + h0 + akc * 8;
            aH[rr] = *(const uint4*)(ahi + so);
            aM[rr] = *(const uint4*)(amd + so);
            aL[rr] = *(const uint4*)(alo + so);
        }
        #pragma unroll
        for (int rr = 0; rr < 2; ++rr) {
            const int kc = bkc0 + rr * 2;
            const float* wp = W + (size_t)(h0 + kc * 8) * HSZ + c0 + bcol;
            #pragma unroll
            for (int j = 0; j < 8; ++j) bx[rr][j] = wp[(size_t)j * HSZ];
        }
        __syncthreads();
        #pragma unroll
        for (int rr = 0; rr < 2; ++rr) {
            const int row = arow + rr * 64;
            *(uint4*)(Ah + row * 40 + akc * 8) = aH[rr];
            *(uint4*)(Am + row * 40 + akc * 8) = aM[rr];
            *(uint4*)(Al + row * 40 + akc * 8) = aL[rr];
        }
        #pragma unroll
        for (int rr = 0; rr < 2; ++rr) {
            const int kc = bkc0 + rr * 2;
            ushort hh[8], mm[8], ll[8];
            #pragma unroll
            for (int j = 0; j < 8; ++j) {
                float x = bx[rr][j];
                ushort h = f2bf(x);
                float r1 = x - bf2f(h);
                ushort m = f2bf(r1);
                hh[j] = h; mm[j] = m; ll[j] = f2bf(r1 - bf2f(m));
            }
            *(uint4*)(Bh + bcol * 40 + kc * 8) = pk8(hh);
            *(uint4*)(Bm + bcol * 40 + kc * 8) = pk8(mm);
            *(uint4*)(Bl + bcol * 40 + kc * 8) = pk8(ll);
        }
        __syncthreads();
        bf16x8 a1[4], a2[4], a3[4];
        #pragma unroll
        for (int i = 0; i < 4; ++i) {
            const int row = wrow * 64 + i * 16 + fr;
            a1[i] = *(const bf16x8*)(Ah + row * 40 + fg * 8);
            a2[i] = *(const bf16x8*)(Am + row * 40 + fg * 8);
            a3[i] = *(const bf16x8*)(Al + row * 40 + fg * 8);
        }
        #pragma unroll
        for (int j = 0; j < 4; ++j) {
            const int cr = wcol * 64 + j * 16 + fr;
            bf16x8 b1 = *(const bf16x8*)(Bh + cr * 40 + fg * 8);
            bf16x8 b2 = *(const bf16x8*)(Bm + cr * 40 + fg * 8);
            bf16x8 b3 = *(const bf16x8*)(Bl + cr * 40 + fg * 8);
            #pragma unroll
            for (int i = 0; i < 4; ++i) {
                acc[i][j] = __builtin_amdgcn_mfma_f32_16x16x32_bf16(a1[i], b1, acc[i][j], 0, 0, 0);
                acc[i][j] = __builtin_amdgcn_mfma_f32_16x16x32_bf16(a1[i], b2, acc[i][j], 0, 0, 0);
                acc[i][j] = __builtin_amdgcn_mfma_f32_16x16x32_bf16(a2[i], b1, acc[i][j], 0, 0, 0);
                acc[i][j] = __builtin_amdgcn_mfma_f32_16x16x32_bf16(a1[i], b3, acc[i][j], 0, 0, 0);
                acc[i][j] = __builtin_amdgcn_mfma_f32_16x16x32_bf16(a3[i], b1, acc[i][j], 0, 0, 0);
                acc[i][j] = __builtin_amdgcn_mfma_f32_16x16x32_bf16(a2[i], b2, acc[i][j], 0, 0, 0);
            }
        }
    }
    #pragma unroll
    for (int i = 0; i < 4; ++i)
        #pragma unroll
        for (int j = 0; j < 4; ++j)
            #pragma unroll
            for (int r = 0; r < 4; ++r) {
                const int trow = wrow * 64 + i * 16 + fg * 4 + r;
                const int dd   = wcol * 64 + j * 16 + fr;
                C[(size_t)(t0 + trow) * HSZ + c0 + dd] = acc[i][j][r];
            }
}

// ---------------------------------------------------------------------------
__global__ __launch_bounds__(256) void pcpy_dot(
    const float* __restrict__ C, const float* __restrict__ ctx,
    const float* __restrict__ bc, float* __restrict__ out)
{
    const int t = blockIdx.x, tid = threadIdx.x;
    const float4 c4 = *(const float4*)(C + (size_t)t * HSZ + tid * 4);
    const float4 x4 = *(const float4*)(ctx + (size_t)t * HSZ + tid * 4);
    const float4 b4 = *(const float4*)(bc + tid * 4);
    float p = (c4.x + b4.x) * x4.x + (c4.y + b4.y) * x4.y
            + (c4.z + b4.z) * x4.z + (c4.w + b4.w) * x4.w;
    #pragma unroll
    for (int off = 32; off > 0; off >>= 1) p += __shfl_down(p, off, 64);
    __shared__ float r4[4];
    if ((tid & 63) == 0) r4[tid >> 6] = p;
    __syncthreads();
    if (tid == 0) out[t] = r4[0] + r4[1] + r4[2] + r4[3];
}

// ---------------------------------------------------------------------------
// head_pre: SINGLE-PASS bf16 logits GEMM, A and B both via global_load_lds
// (double-buffered, swizzled layout), + exp/sum/top-3 + P@emb.
// LDS: A0@0 A1@8192 B0@16384 B1@24576 (staging, 32KB)
//   epilogue alias: P@0 [128][136]us (34816), EM@34816 [128][72]us (->53248)
//   stats: wsum@53248 [128][2], bval@54272 [128][2][3], bidx@57344 -> 60416
// element (row,k): pair=row>>1, ch=(((row&1)<<2)|(k>>3))^(pair&7)^((pair>>3)&3)
//   byte = pair*128 + ch*16 + (k&7)*2
// ---------------------------------------------------------------------------
__global__ __launch_bounds__(256, 2) void head_pre(
    const ushort* __restrict__ ctx_hi, const ushort* __restrict__ Wt,
    const float* __restrict__ bias, const float* __restrict__ g,
    const float* __restrict__ emb,
    int V, int ldg, int tps, int n_tiles,
    float* __restrict__ wsW, float* __restrict__ wsBV,
    int* __restrict__ wsBI, float* __restrict__ wsE)
{
    __shared__ __align__(16) char smem[60416];
    ushort* Pl = (ushort*)smem;
    ushort* EM = (ushort*)(smem + 34816);
    float* sm_wsum = (float*)(smem + 53248);
    float* sm_bval = (float*)(smem + 54272);
    int*   sm_bidx = (int*)(smem + 57344);

    const int tid  = threadIdx.x;
    const int lane = tid & 63;
    const int fr   = lane & 15;
    const int fg   = lane >> 4;
    const int wv   = tid >> 6;
    const int wrow = wv >> 1;
    const int wcol = wv & 1;
    const int split = (int)blockIdx.x;
    const int t0    = (int)blockIdx.y * 128;

    if (tid < 128) {
        sm_wsum[tid * 2] = 0.f; sm_wsum[tid * 2 + 1] = 0.f;
        #pragma unroll
        for (int s = 0; s < 3; ++s) {
            sm_bval[(tid * 2) * 3 + s] = -INFINITY;
            sm_bval[(tid * 2 + 1) * 3 + s] = -INFINITY;
            sm_bidx[(tid * 2) * 3 + s] = 0;
            sm_bidx[(tid * 2 + 1) * 3 + s] = 0;
        }
    }

    // fragment read offsets
    const int chunkRd0 = (((fr & 1) << 2) | fg) ^ ((fr >> 1) & 7);
    int aRd[4], bRd[4];
    #pragma unroll
    for (int i = 0; i < 4; ++i) {
        aRd[i] = wrow * 4096 + i * 1024 + (fr >> 1) * 128 + ((chunkRd0 ^ i) << 4);
        bRd[i] = wcol * 4096 + i * 1024 + (fr >> 1) * 128 + ((chunkRd0 ^ i) << 4);
    }

    // gll lane constants (pre-XOR'd source -> linear dest reproduces layout)
    const int v_ = (lane & 7) ^ (lane >> 3) ^ (wv & 3);
    int rowq[2];
    #pragma unroll
    for (int q = 0; q < 2; ++q)
        rowq[q] = 2 * (q * 32 + wv * 8 + (lane >> 3)) + (v_ >> 2);
    const int glK = (v_ & 3) * 8;
    const size_t srcA0 = (size_t)(t0 + rowq[0]) * HSZ + glK;
    const size_t srcA1 = (size_t)(t0 + rowq[1]) * HSZ + glK;
    const int dA0 = wv * 1024, dA1 = 4096 + wv * 1024;

    f32x4 zero4 = {0.f, 0.f, 0.f, 0.f};
    f32x4 Eacc[4][4];
    #pragma unroll
    for (int i = 0; i < 4; ++i)
        #pragma unroll
        for (int j = 0; j < 4; ++j) Eacc[i][j] = zero4;

    int tbeg = split * tps;
    int tend = tbeg + tps; if (tend > n_tiles) tend = n_tiles;

    for (int tt = tbeg; tt < tend; ++tt) {
        const int c0 = tt * 128;
        const size_t srcB0 = (size_t)(c0 + rowq[0]) * HSZ + glK;
        const size_t srcB1 = (size_t)(c0 + rowq[1]) * HSZ + glK;
        f32x4 acc[4][4];
        #pragma unroll
        for (int i = 0; i < 4; ++i)
            #pragma unroll
            for (int j = 0; j < 4; ++j) acc[i][j] = zero4;

        // stage step 0 into buffers 0
        GLL16(ctx_hi + srcA0, smem + dA0);
        GLL16(ctx_hi + srcA1, smem + dA1);
        GLL16(Wt + srcB0, smem + 16384 + dA0);
        GLL16(Wt + srcB1, smem + 16384 + dA1);
        __syncthreads();

        for (int ks = 0; ks < 32; ++ks) {
            const int cur = ks & 1;
            if (ks < 31) {
                const int so = (ks + 1) * 32;
                char* an = smem + (cur ^ 1) * 8192;
                char* bn = smem + 16384 + (cur ^ 1) * 8192;
                GLL16(ctx_hi + srcA0 + so, an + dA0);
                GLL16(ctx_hi + srcA1 + so, an + dA1);
                GLL16(Wt + srcB0 + so, bn + dA0);
                GLL16(Wt + srcB1 + so, bn + dA1);
            }
            char* bA = smem + cur * 8192;
            char* bB = smem + 16384 + cur * 8192;
            bf16x8 ah[4], bh[4];
            #pragma unroll
            for (int i = 0; i < 4; ++i) ah[i] = *(const bf16x8*)(bA + aRd[i]);
            #pragma unroll
            for (int j = 0; j < 4; ++j) bh[j] = *(const bf16x8*)(bB + bRd[j]);
            #pragma unroll
            for (int j = 0; j < 4; ++j)
                #pragma unroll
                for (int i = 0; i < 4; ++i)
                    acc[i][j] = __builtin_amdgcn_mfma_f32_16x16x32_bf16(ah[i], bh[j], acc[i][j], 0, 0, 0);
            __syncthreads();
        }

        // ---- epilogue: bias + gumbel + exp, P -> LDS, Z + top-3 stats ----
        float bias4[4];
        #pragma unroll
        for (int j = 0; j < 4; ++j) {
            const int gc = c0 + wcol * 64 + j * 16 + fr;
            bias4[j] = (gc < V) ? bias[gc] : 0.f;
        }
        #pragma unroll
        for (int i = 0; i < 4; ++i) {
            #pragma unroll
            for (int r = 0; r < 4; ++r) {
                const int trow = wrow * 64 + i * 16 + fg * 4 + r;
                const float* gp = g + (size_t)(t0 + trow) * ldg + c0 + wcol * 64 + fr;
                float esum = 0.f;
                float t3v[3] = {-INFINITY, -INFINITY, -INFINITY};
                int   t3i[3] = {0, 0, 0};
                #pragma unroll
                for (int j = 0; j < 4; ++j) {
                    const int gc = c0 + wcol * 64 + j * 16 + fr;
                    float e = 0.f;
                    if (gc < V) {
                        const float s = acc[i][j][r] + bias4[j] + gp[j * 16];
                        e = __expf(s);
                        esum += e;
                        ins3(s, gc, t3v, t3i);
                    }
                    Pl[trow * 136 + wcol * 64 + j * 16 + fr] = f2bf(e);
                }
                #pragma unroll
                for (int off = 1; off < 16; off <<= 1) {
                    float o0 = __shfl_xor(t3v[0], off, 64);
                    float o1 = __shfl_xor(t3v[1], off, 64);
                    float o2 = __shfl_xor(t3v[2], off, 64);
                    int q0 = __shfl_xor(t3i[0], off, 64);
                    int q1 = __shfl_xor(t3i[1], off, 64);
                    int q2 = __shfl_xor(t3i[2], off, 64);
                    esum += __shfl_xor(esum, off, 64);
                    ins3(o0, q0, t3v, t3i);
                    ins3(o1, q1, t3v, t3i);
                    ins3(o2, q2, t3v, t3i);
                }
                if (fr == 0) {
                    const int sb = (trow * 2 + wcol) * 3;
                    sm_wsum[trow * 2 + wcol] += esum;
                    float sh[3] = {sm_bval[sb], sm_bval[sb + 1], sm_bval[sb + 2]};
                    int shi[3] = {sm_bidx[sb], sm_bidx[sb + 1], sm_bidx[sb + 2]};
                    ins3(t3v[0], t3i[0], sh, shi);
                    ins3(t3v[1], t3i[1], sh, shi);
                    ins3(t3v[2], t3i[2], sh, shi);
                    sm_bval[sb] = sh[0]; sm_bval[sb + 1] = sh[1]; sm_bval[sb + 2] = sh[2];
                    sm_bidx[sb] = shi[0]; sm_bidx[sb + 1] = shi[1]; sm_bidx[sb + 2] = shi[2];
                }
            }
        }

        // ---- E-GEMM in two 64-col halves ----
        #pragma unroll
        for (int hf = 0; hf < 2; ++hf) {
            __syncthreads();
            #pragma unroll
            for (int rr = 0; rr < 4; ++rr) {
                const int task = tid + rr * 256;
                const int dd0 = task & 127;
                const int cc = task >> 7;
                ushort o8[8];
                #pragma unroll
                for (int j = 0; j < 8; ++j) {
                    const int gc = c0 + hf * 64 + cc * 8 + j;
                    o8[j] = (gc < V) ? f2bf(emb[(size_t)gc * DIM + dd0]) : (ushort)0;
                }
                *(uint4*)(EM + dd0 * 72 + cc * 8) = pk8(o8);
            }
            __syncthreads();
            #pragma unroll
            for (int ksb = 0; ksb < 2; ++ksb) {
                bf16x8 ap[4];
                #pragma unroll
                for (int i = 0; i < 4; ++i) {
                    const int row = wrow * 64 + i * 16 + fr;
                    ap[i] = *(const bf16x8*)(Pl + row * 136 + hf * 64 + ksb * 32 + fg * 8);
                }
                #pragma unroll
                for (int j = 0; j < 4; ++j) {
                    const int dd = wcol * 64 + j * 16 + fr;
                    bf16x8 eb = *(const bf16x8*)(EM + dd * 72 + ksb * 32 + fg * 8);
                    #pragma unroll
                    for (int i = 0; i < 4; ++i)
                        Eacc[i][j] = __builtin_amdgcn_mfma_f32_16x16x32_bf16(ap[i], eb, Eacc[i][j], 0, 0, 0);
                }
            }
        }
        __syncthreads();
    }

    __syncthreads();
    if (tid < 128) {
        const int sb0 = (tid * 2) * 3, sb1 = (tid * 2 + 1) * 3;
        float v3[3] = {sm_bval[sb0], sm_bval[sb0 + 1], sm_bval[sb0 + 2]};
        int i3[3] = {sm_bidx[sb0], sm_bidx[sb0 + 1], sm_bidx[sb0 + 2]};
        ins3(sm_bval[sb1], sm_bidx[sb1], v3, i3);
        ins3(sm_bval[sb1 + 1], sm_bidx[sb1 + 1], v3, i3);
        ins3(sm_bval[sb1 + 2], sm_bidx[sb1 + 2], v3, i3);
        const size_t o = (size_t)split * TOK + t0 + tid;
        wsW[o] = sm_wsum[tid * 2] + sm_wsum[tid * 2 + 1];
        #pragma unroll
        for (int s = 0; s < 3; ++s) { wsBV[o * 3 + s] = v3[s]; wsBI[o * 3 + s] = i3[s]; }
    }
    #pragma unroll
    for (int i = 0; i < 4; ++i)
        #pragma unroll
        for (int j = 0; j < 4; ++j)
            #pragma unroll
            for (int r = 0; r < 4; ++r) {
                const int trow = wrow * 64 + i * 16 + fg * 4 + r;
                const int dd   = wcol * 64 + j * 16 + fr;
                wsE[((size_t)split * TOK + t0 + trow) * DIM + dd] = Eacc[i][j][r];
            }
}

// ---------------------------------------------------------------------------
// head_fb: proven r4 2-term head (fallback when ws too small). Writes slot-0
// of the 3-slot stat format.
// ---------------------------------------------------------------------------
__global__ __launch_bounds__(256, 2) void head_fb(
    const ushort* __restrict__ ctx_hi, const ushort* __restrict__ ctx_lo,
    const float* __restrict__ W, const float* __restrict__ bias,
    const float* __restrict__ g, const float* __restrict__ emb,
    int V, int ldg, int tps, int n_tiles,
    float* __restrict__ wsW, float* __restrict__ wsBV,
    int* __restrict__ wsBI, float* __restrict__ wsE)
{
    __shared__ __align__(16) char smem[56320];
    ushort* Pl = (ushort*)smem;
    ushort* EM = (ushort*)(smem + 34816);
    float* sm_wsum = (float*)(smem + 53248);
    float* sm_bval = (float*)(smem + 54272);
    int*   sm_bidx = (int*)(smem + 55296);

    const int tid  = threadIdx.x;
    const int lane = tid & 63;
    const int fr   = lane & 15;
    const int fg   = lane >> 4;
    const int wv   = tid >> 6;
    const int wrow = wv >> 1;
    const int wcol = wv & 1;
    const int split = (int)blockIdx.x;
    const int t0    = (int)blockIdx.y * 128;

    if (tid < 128) {
        sm_wsum[tid * 2] = 0.f;        sm_wsum[tid * 2 + 1] = 0.f;
        sm_bval[tid * 2] = -INFINITY;  sm_bval[tid * 2 + 1] = -INFINITY;
        sm_bidx[tid * 2] = 0;          sm_bidx[tid * 2 + 1] = 0;
    }

    const int chunkRd  = (((fr & 1) << 2) | fg) ^ ((fr >> 1) & 7);
    const int laneAoff = wrow * 4096 + (fr >> 1) * 128 + chunkRd * 16;
    const int laneBoff = wcol * 4096 + (fr >> 1) * 128 + chunkRd * 16;

    const int cfA   = (lane & 7) ^ (lane >> 3);
    const int glTok = (wv * 8 + (lane >> 3)) * 2 + (cfA >> 2);
    const int glK   = (cfA & 3) * 8;
    const int glDst = wv * 1024;

    const int c4 = (tid & 31) * 4;
    const int hb = (tid >> 5) * 2;
    int wb01[4], wb23[4];
    #pragma unroll
    for (int i = 0; i < 4; ++i) {
        const int col = c4 + i;
        const int pair = col >> 1;
        const int ch01 = (((col & 1) << 2) | (hb >> 3)) ^ (pair & 7);
        const int ch23 = (((col & 1) << 2) | (2 + (hb >> 3))) ^ (pair & 7);
        wb01[i] = pair * 128 + ch01 * 16 + (hb & 7) * 2;
        wb23[i] = pair * 128 + ch23 * 16 + (hb & 7) * 2;
    }

    f32x4 zero4 = {0.f, 0.f, 0.f, 0.f};
    f32x4 Eacc[4][4];
    #pragma unroll
    for (int i = 0; i < 4; ++i)
        #pragma unroll
        for (int j = 0; j < 4; ++j) Eacc[i][j] = zero4;

    int tbeg = split * tps;
    int tend = tbeg + tps; if (tend > n_tiles) tend = n_tiles;

    #define STAGE_A(STEP, BASE) do {                                               \
        const size_t ro_ = (size_t)(t0 + glTok) * HSZ + (size_t)(STEP) * 32 + glK; \
        GLL16(ctx_hi + ro_,          (BASE) + glDst);                              \
        GLL16(ctx_hi + ro_ + 65536,  (BASE) + 4096 + glDst);                       \
        GLL16(ctx_lo + ro_,          (BASE) + 8192 + glDst);                       \
        GLL16(ctx_lo + ro_ + 65536,  (BASE) + 12288 + glDst);                      \
    } while (0)

    #define LOAD_W(STEP, VV) do {                                                 \
        const int gc_ = c0 + c4;                                                   \
        if (gc_ + 3 < V) {                                                         \
            const float* p_ = W + (size_t)((STEP) * 32 + hb) * V + gc_;            \
            VV[0] = *(const float4*)p_;                                            \
            VV[1] = *(const float4*)(p_ + V);                                      \
            VV[2] = *(const float4*)(p_ + 16 * (size_t)V);                         \
            VV[3] = *(const float4*)(p_ + 17 * (size_t)V);                         \
        } else {                                                                   \
            float4 z_ = {0.f, 0.f, 0.f, 0.f};                                      \
            VV[0] = z_; VV[1] = z_; VV[2] = z_; VV[3] = z_;                        \
        }                                                                          \
    } while (0)

    #define CONV_W(VV) do {                                                       \
        _Pragma("unroll")                                                          \
        for (int i_ = 0; i_ < 4; ++i_) {                                           \
            const float* fv0 = (const float*)&VV[0];                               \
            const float* fv1 = (const float*)&VV[1];                               \
            const float* fv2 = (const float*)&VV[2];                               \
            const float* fv3 = (const float*)&VV[3];                               \
            float a0 = fv0[i_], a1 = fv1[i_], a2 = fv2[i_], a3 = fv3[i_];          \
            ushort h0b = f2bf(a0); ushort l0b = f2bf(a0 - bf2f(h0b));              \
            ushort h1b = f2bf(a1); ushort l1b = f2bf(a1 - bf2f(h1b));              \
            ushort h2b = f2bf(a2); ushort l2b = f2bf(a2 - bf2f(h2b));              \
            ushort h3b = f2bf(a3); ushort l3b = f2bf(a3 - bf2f(h3b));              \
            *(uint*)(smem + 32768 + wb01[i_]) = (uint)h0b | ((uint)h1b << 16);     \
            *(uint*)(smem + 32768 + wb23[i_]) = (uint)h2b | ((uint)h3b << 16);     \
            *(uint*)(smem + 40960 + wb01[i_]) = (uint)l0b | ((uint)l1b << 16);     \
            *(uint*)(smem + 40960 + wb23[i_]) = (uint)l2b | ((uint)l3b << 16);     \
        }                                                                          \
    } while (0)

    for (int tt = tbeg; tt < tend; ++tt) {
        const int c0 = tt * 128;
        f32x4 acc[4][4];
        #pragma unroll
        for (int i = 0; i < 4; ++i)
            #pragma unroll
            for (int j = 0; j < 4; ++j) acc[i][j] = zero4;

        STAGE_A(0, smem);
        {
            float4 v0[4];
            LOAD_W(0, v0);
            CONV_W(v0);
        }
        __syncthreads();

        for (int ks = 0; ks < 32; ++ks) {
            const int cur = ks & 1;
            const bool more = (ks + 1) < 32;
            float4 vn[4];
            if (more) {
                STAGE_A(ks + 1, smem + (cur ^ 1) * 16384);
                LOAD_W(ks + 1, vn);
            }
            char* bA = smem + cur * 16384;
            bf16x8 ah[4], al[4];
            #pragma unroll
            for (int i = 0; i < 4; ++i) {
                ah[i] = *(const bf16x8*)(bA + laneAoff + i * 1024);
                al[i] = *(const bf16x8*)(bA + 8192 + laneAoff + i * 1024);
            }
            #pragma unroll
            for (int j = 0; j < 4; ++j) {
                bf16x8 vbh = *(const bf16x8*)(smem + 32768 + laneBoff + j * 1024);
                bf16x8 vbl = *(const bf16x8*)(smem + 40960 + laneBoff + j * 1024);
                #pragma unroll
                for (int i = 0; i < 4; ++i) {
                    acc[i][j] = __builtin_amdgcn_mfma_f32_16x16x32_bf16(ah[i], vbh, acc[i][j], 0, 0, 0);
                    acc[i][j] = __builtin_amdgcn_mfma_f32_16x16x32_bf16(ah[i], vbl, acc[i][j], 0, 0, 0);
                    acc[i][j] = __builtin_amdgcn_mfma_f32_16x16x32_bf16(al[i], vbh, acc[i][j], 0, 0, 0);
                }
            }
            __syncthreads();
            if (more) CONV_W(vn);
            __syncthreads();
        }

        float bias4[4];
        #pragma unroll
        for (int j = 0; j < 4; ++j) {
            const int gc = c0 + wcol * 64 + j * 16 + fr;
            bias4[j] = (gc < V) ? bias[gc] : 0.f;
        }
        #pragma unroll
        for (int i = 0; i < 4; ++i) {
            #pragma unroll
            for (int r = 0; r < 4; ++r) {
                const int trow = wrow * 64 + i * 16 + fg * 4 + r;
                const float* gp = g + (size_t)(t0 + trow) * ldg + c0 + wcol * 64 + fr;
                float esum = 0.f, mx = -INFINITY;
                int mi = 0;
                #pragma unroll
                for (int j = 0; j < 4; ++j) {
                    const int gc = c0 + wcol * 64 + j * 16 + fr;
                    float e = 0.f;
                    if (gc < V) {
                        const float s = acc[i][j][r] + bias4[j] + gp[j * 16];
                        e = __expf(s);
                        esum += e;
                        if (s > mx) { mx = s; mi = gc; }
                    }
                    Pl[trow * 136 + wcol * 64 + j * 16 + fr] = f2bf(e);
                }
                #pragma unroll
                for (int off = 1; off < 16; off <<= 1) {
                    const float ov = __shfl_xor(mx, off, 64);
                    const int   oi = __shfl_xor(mi, off, 64);
                    esum += __shfl_xor(esum, off, 64);
                    if (ov > mx || (ov == mx && oi < mi)) { mx = ov; mi = oi; }
                }
                if (fr == 0) {
                    sm_wsum[trow * 2 + wcol] += esum;
                    const float cb = sm_bval[trow * 2 + wcol];
                    const int   ci = sm_bidx[trow * 2 + wcol];
                    if (mx > cb || (mx == cb && mi < ci)) {
                        sm_bval[trow * 2 + wcol] = mx;
                        sm_bidx[trow * 2 + wcol] = mi;
                    }
                }
            }
        }

        #pragma unroll
        for (int hf = 0; hf < 2; ++hf) {
            __syncthreads();
            #pragma unroll
            for (int rr = 0; rr < 4; ++rr) {
                const int task = tid + rr * 256;
                const int dd0 = task & 127;
                const int cc = task >> 7;
                ushort o8[8];
                #pragma unroll
                for (int j = 0; j < 8; ++j) {
                    const int gc = c0 + hf * 64 + cc * 8 + j;
                    o8[j] = (gc < V) ? f2bf(emb[(size_t)gc * DIM + dd0]) : (ushort)0;
                }
                *(uint4*)(EM + dd0 * 72 + cc * 8) = pk8(o8);
            }
            __syncthreads();
            #pragma unroll
            for (int ksb = 0; ksb < 2; ++ksb) {
                bf16x8 ap[4];
                #pragma unroll
                for (int i = 0; i < 4; ++i) {
                    const int row = wrow * 64 + i * 16 + fr;
                    ap[i] = *(const bf16x8*)(Pl + row * 136 + hf * 64 + ksb * 32 + fg * 8);
                }
                #pragma unroll
                for (int j = 0; j < 4; ++j) {
                    const int dd = wcol * 64 + j * 16 + fr;
                    bf16x8 eb = *(const bf16x8*)(EM + dd * 72 + ksb * 32 + fg * 8);
                    #pragma unroll
                    for (int i = 0; i < 4; ++i)
                        Eacc[i][j] = __builtin_amdgcn_mfma_f32_16x16x32_bf16(ap[i], eb, Eacc[i][j], 0, 0, 0);
                }
            }
        }
        __syncthreads();
    }

    __syncthreads();
    if (tid < 128) {
        const float wsv = sm_wsum[tid * 2] + sm_wsum[tid * 2 + 1];
        const float b0 = sm_bval[tid * 2], b1 = sm_bval[tid * 2 + 1];
        const int   i0 = sm_bidx[tid * 2], i1 = sm_bidx[tid * 2 + 1];
        float bv; int bi;
        if (b0 > b1 || (b0 == b1 && i0 < i1)) { bv = b0; bi = i0; }
        else                                   { bv = b1; bi = i1; }
        const size_t o = (size_t)split * TOK + t0 + tid;
        wsW[o] = wsv;
        wsBV[o * 3] = bv; wsBV[o * 3 + 1] = -INFINITY; wsBV[o * 3 + 2] = -INFINITY;
        wsBI[o * 3] = bi; wsBI[o * 3 + 1] = 0; wsBI[o * 3 + 2] = 0;
    }
    #pragma unroll
    for (int i = 0; i < 4; ++i)
        #pragma unroll
        for (int j = 0; j < 4; ++j)
            #pragma unroll
            for (int r = 0; r < 4; ++r) {
                const int trow = wrow * 64 + i * 16 + fg * 4 + r;
                const int dd   = wcol * 64 + j * 16 + fr;
                wsE[((size_t)split * TOK + t0 + trow) * DIM + dd] = Eacc[i][j][r];
            }
    #undef STAGE_A
    #undef LOAD_W
    #undef CONV_W
}

// ---------------------------------------------------------------------------
// combine2: merge partials, optional exact recompute of top-3 candidates,
// copy column, output selection.
// ---------------------------------------------------------------------------
__global__ __launch_bounds__(128) void combine2(
    const int* __restrict__ inp_word, const float* __restrict__ masks,
    const int* __restrict__ spt_mask, const int* __restrict__ tgt_ids,
    const float* __restrict__ word_emb, const float* __restrict__ pcpy,
    const float* __restrict__ g_nrm, const float* __restrict__ g_spt,
    const float* __restrict__ ctx,
    const float* __restrict__ b_nrm, const float* __restrict__ b_spt,
    const ushort* __restrict__ WtNh, const void* __restrict__ WtNl,
    const ushort* __restrict__ WtSh, const void* __restrict__ WtSl,
    const float* __restrict__ nW, const float* __restrict__ nBV,
    const int* __restrict__ nBI, const float* __restrict__ nE, int NVn,
    const float* __restrict__ sW, const float* __restrict__ sBV,
    const int* __restrict__ sBI, const float* __restrict__ sE, int NVs,
    float* __restrict__ out, int recomp, int lf32)
{
    __shared__ double sred[2][6];
    __shared__ float sfin[6];
    const int t = (int)blockIdx.x;
    const int d = (int)threadIdx.x;

    float Wn = 0.f, En = 0.f;
    float cv[3] = {-INFINITY, -INFINITY, -INFINITY}; int ci[3] = {0, 0, 0};
    for (int v = 0; v < NVn; ++v) {
        const size_t o = (size_t)v * TOK + t;
        Wn += nW[o];
        En += nE[o * DIM + d];
        #pragma unroll
        for (int s = 0; s < 3; ++s) ins3(nBV[o * 3 + s], nBI[o * 3 + s], cv, ci);
    }
    float Ws = 0.f, Es = 0.f;
    float dv[3] = {-INFINITY, -INFINITY, -INFINITY}; int di[3] = {0, 0, 0};
    for (int v = 0; v < NVs; ++v) {
        const size_t o = (size_t)v * TOK + t;
        Ws += sW[o];
        Es += sE[o * DIM + d];
        #pragma unroll
        for (int s = 0; s < 3; ++s) ins3(sBV[o * 3 + s], sBI[o * 3 + s], dv, di);
    }

    float bnv, bsv; int bni, bsi;
    if (recomp) {
        float cxv[8];
        #pragma unroll
        for (int q = 0; q < 8; ++q) cxv[q] = ctx[(size_t)t * HSZ + d * 8 + q];
        double part[6] = {0, 0, 0, 0, 0, 0};
        #pragma unroll
        for (int c = 0; c < 3; ++c) {
            if (cv[c] > -1e30f) {
                const ushort* ph = WtNh + (size_t)ci[c] * HSZ + d * 8;
                double p = 0.0;
                if (lf32) {
                    const float* pl = (const float*)WtNl + (size_t)ci[c] * HSZ + d * 8;
                    #pragma unroll
                    for (int q = 0; q < 8; ++q)
                        p += (double)cxv[q] * ((double)bf2f(ph[q]) + (double)pl[q]);
                } else {
                    const ushort* pl = (const ushort*)WtNl + (size_t)ci[c] * HSZ + d * 8;
                    #pragma unroll
                    for (int q = 0; q < 8; ++q)
                        p += (double)cxv[q] * ((double)bf2f(ph[q]) + (double)bf2f(pl[q]));
                }
                part[c] = p;
            }
        }
        #pragma unroll
        for (int c = 0; c < 3; ++c) {
            if (dv[c] > -1e30f) {
                const ushort* ph = WtSh + (size_t)di[c] * HSZ + d * 8;
                double p = 0.0;
                if (lf32) {
                    const float* pl = (const float*)WtSl + (size_t)di[c] * HSZ + d * 8;
                    #pragma unroll
                    for (int q = 0; q < 8; ++q)
                        p += (double)cxv[q] * ((double)bf2f(ph[q]) + (double)pl[q]);
                } else {
                    const ushort* pl = (const ushort*)WtSl + (size_t)di[c] * HSZ + d * 8;
                    #pragma unroll
                    for (int q = 0; q < 8; ++q)
                        p += (double)cxv[q] * ((double)bf2f(ph[q]) + (double)bf2f(pl[q]));
                }
                part[3 + c] = p;
            }
        }
        #pragma unroll
        for (int c = 0; c < 6; ++c)
            for (int off = 32; off > 0; off >>= 1)
                part[c] += __shfl_down(part[c], off, 64);
        if ((d & 63) == 0) {
            #pragma unroll
            for (int c = 0; c < 6; ++c) sred[d >> 6][c] = part[c];
        }
        __syncthreads();
        if (d == 0) {
            #pragma unroll
            for (int c = 0; c < 3; ++c) {
                sfin[c] = (cv[c] > -1e30f)
                    ? (float)(sred[0][c] + sred[1][c]) + b_nrm[ci[c]]
                      + g_nrm[(size_t)t * (NWRDC + 1) + ci[c]]
                    : -INFINITY;
                sfin[3 + c] = (dv[c] > -1e30f)
                    ? (float)(sred[0][3 + c] + sred[1][3 + c]) + b_spt[di[c]]
                      + g_spt[(size_t)t * NTGTC + di[c]]
                    : -INFINITY;
            }
        }
        __syncthreads();
        bnv = sfin[0]; bni = ci[0];
        #pragma unroll
        for (int c = 1; c < 3; ++c)
            if (sfin[c] > bnv || (sfin[c] == bnv && ci[c] < bni)) { bnv = sfin[c]; bni = ci[c]; }
        bsv = sfin[3]; bsi = di[0];
        #pragma unroll
        for (int c = 1; c < 3; ++c)
            if (sfin[3 + c] > bsv || (sfin[3 + c] == bsv && di[c] < bsi)) { bsv = sfin[3 + c]; bsi = di[c]; }
    } else {
        bnv = cv[0]; bni = ci[0]; bsv = dv[0]; bsi = di[0];
    }

    const int iw = inp_word[t];
    const float sc = pcpy[t] + g_nrm[(size_t)t * (NWRDC + 1) + NWRDC];
    const float ec = __expf(sc);
    Wn += ec;
    En += ec * word_emb[(size_t)iw * DIM + d];
    const int ynrm = (sc > bnv) ? iw : bni;
    const int yspt = tgt_ids[bsi];

    const float sptf = (float)spt_mask[t];
    const float nrmf = (1.f - sptf) * masks[t];

    float eo; int obf;
    if (sptf > 0.f)      { eo = Es / Ws; obf = yspt; }
    else if (nrmf > 0.f) { eo = En / Wn; obf = ynrm; }
    else                 { obf = iw; eo = word_emb[(size_t)iw * DIM + d]; }

    out[(size_t)t * DIM + d] = eo;
    if (d == 0) {
        out[(size_t)TOK * DIM + t]       = (float)obf;
        out[(size_t)TOK * DIM + TOK + t] = sptf;
    }
}

// ---------------------------------------------------------------------------
extern "C" void kernel_launch(void* const* d_in, const int* in_sizes, int n_in,
                              void* d_out, int out_size, void* d_ws, size_t ws_size,
                              hipStream_t stream)
{
    const int*   inp_word = (const int*)d_in[0];
    const float* masks    = (const float*)d_in[1];
    const int*   spt_mask = (const int*)d_in[2];
    const int*   tgt_ids  = (const int*)d_in[3];
    const float* ctx      = (const float*)d_in[4];
    const float* W_spt    = (const float*)d_in[5];
    const float* b_spt    = (const float*)d_in[6];
    const float* W_nrm    = (const float*)d_in[7];
    const float* b_nrm    = (const float*)d_in[8];
    const float* W_cpy    = (const float*)d_in[9];
    const float* b_cpy    = (const float*)d_in[10];
    const float* word_emb = (const float*)d_in[11];
    const float* word_emb_tgt = (const float*)d_in[12];
    const float* g_spt    = (const float*)d_in[13];
    const float* g_nrm    = (const float*)d_in[14];
    float* out = (float*)d_out;

    char* wsb = (char*)d_ws;
    // fixed offsets
    const size_t O_CTXH = 4096;
    const size_t O_CTXM = 4096 + 2097152;
    const size_t O_CTXL = 4096 + 4194304;
    const size_t O_WTNH = 6295552;                 // 65536000
    const size_t O_WTSH = 71831552;                // 4194304
    const size_t O_L    = 76025856;
    // mode2: WtNl f32 @O_L (131072000), WtSl f32 @207097856 (8388608), region @215486464
    // mode1: WtNl bf16 @O_L (65536000), WtSl bf16 @141561856 (4194304), region @145756160
    // mode0: region @6295552
    const size_t per_split = 552960;               // 1024*(1+3+3+128)*4

    struct Pair { int n, s; };
    const Pair pairs[] = {{64,8},{48,8},{32,8},{24,8},{16,8},{8,4},{4,2},{2,1},{1,1}};
    auto pick = [&](size_t base, int& NVn, int& NVs) -> bool {
        for (int pi = 0; pi < 9; ++pi) {
            size_t reg = (size_t)(pairs[pi].n + pairs[pi].s) * per_split;
            if (reg < 4194304) reg = 4194304;
            if (ws_size >= base + reg) { NVn = pairs[pi].n; NVs = pairs[pi].s; return true; }
        }
        return false;
    };

    int mode = 0, NVn = 1, NVs = 1;
    size_t region_off = 6295552;
    int nvn2, nvs2, nvn1, nvs1;
    bool f2 = pick(215486464, nvn2, nvs2);
    bool f1 = pick(145756160, nvn1, nvs1);
    if (f2 && nvn2 >= 16)      { mode = 2; NVn = nvn2; NVs = nvs2; region_off = 215486464; }
    else if (f1 && nvn1 >= 16) { mode = 1; NVn = nvn1; NVs = nvs1; region_off = 145756160; }
    else if (f2)               { mode = 2; NVn = nvn2; NVs = nvs2; region_off = 215486464; }
    else if (f1)               { mode = 1; NVn = nvn1; NVs = nvs1; region_off = 145756160; }
    else {
        mode = 0; region_off = 6295552;
        size_t avail = (ws_size > 6295552) ? (ws_size - 6295552) : 0;
        NVn = 1; NVs = 1;
        for (int pi = 0; pi < 9; ++pi) {
            size_t reg = (size_t)(pairs[pi].n + pairs[pi].s) * per_split;
            if (reg < 4194304) reg = 4194304;
            if (avail >= reg) { NVn = pairs[pi].n; NVs = pairs[pi].s; break; }
        }
    }

    float*  pcpy = (float*)wsb;
    ushort* ctxh = (ushort*)(wsb + O_CTXH);
    ushort* ctxm = (ushort*)(wsb + O_CTXM);
    ushort* ctxl = (ushort*)(wsb + O_CTXL);
    ushort* WtNh = (ushort*)(wsb + O_WTNH);
    ushort* WtSh = (ushort*)(wsb + O_WTSH);
    void* WtNl = (void*)(wsb + O_L);
    void* WtSl = (mode == 2) ? (void*)(wsb + 207097856) : (void*)(wsb + 141561856);
    char* region = wsb + region_off;
    float* Cws = (float*)region;                   // dead after pcpy_dot

    float* nW  = (float*)region;
    float* nBV = nW + (size_t)NVn * TOK;
    int*   nBI = (int*)(nBV + (size_t)NVn * TOK * 3);
    float* nE  = (float*)(nBI + (size_t)NVn * TOK * 3);
    float* sW  = nE + (size_t)NVn * TOK * DIM;
    float* sBV = sW + (size_t)NVs * TOK;
    int*   sBI = (int*)(sBV + (size_t)NVs * TOK * 3);
    float* sE  = (float*)(sBI + (size_t)NVs * TOK * 3);

    const int tps_n = (250 + NVn - 1) / NVn;
    const int tps_s = (16 + NVs - 1) / NVs;

    split_ctx3<<<dim3(TOK * HSZ / 1024), dim3(256), 0, stream>>>(ctx, ctxh, ctxm, ctxl);
    if (mode >= 1) {
        conv_wt<<<dim3(125, 8), dim3(256), 0, stream>>>(W_nrm, NWRDC, WtNh, WtNl, mode == 2);
        conv_wt<<<dim3(8, 8), dim3(256), 0, stream>>>(W_spt, NTGTC, WtSh, WtSl, mode == 2);
    }
    gemm_cpy<<<dim3(8, 8), dim3(256), 0, stream>>>(ctxh, ctxm, ctxl, W_cpy, Cws);
    pcpy_dot<<<dim3(TOK), dim3(256), 0, stream>>>(Cws, ctx, b_cpy, pcpy);
    if (mode >= 1) {
        head_pre<<<dim3(NVn, 8), dim3(256), 0, stream>>>(
            ctxh, WtNh, b_nrm, g_nrm, word_emb, NWRDC, NWRDC + 1,
            tps_n, 250, nW, nBV, nBI, nE);
        head_pre<<<dim3(NVs, 8), dim3(256), 0, stream>>>(
            ctxh, WtSh, b_spt, g_spt, word_emb_tgt, NTGTC, NTGTC,
            tps_s, 16, sW, sBV, sBI, sE);
    } else {
        head_fb<<<dim3(NVn, 8), dim3(256), 0, stream>>>(
            ctxh, ctxm, W_nrm, b_nrm, g_nrm, word_emb, NWRDC, NWRDC + 1,
            tps_n, 250, nW, nBV, nBI, nE);
        head_fb<<<dim3(NVs, 8), dim3(256), 0, stream>>>(
            ctxh, ctxm, W_spt, b_spt, g_spt, word_emb_tgt, NTGTC, NTGTC,
            tps_s, 16, sW, sBV, sBI, sE);
    }
    combine2<<<dim3(TOK), dim3(128), 0, stream>>>(
        inp_word, masks, spt_mask, tgt_ids, word_emb, pcpy, g_nrm, g_spt, ctx,
        b_nrm, b_spt, WtNh, WtNl, WtSh, WtSl,
        nW, nBV, nBI, nE, NVn, sW, sBV, sBI, sE, NVs,
        out, mode >= 1 ? 1 : 0, mode == 2 ? 1 : 0);
    (void)in_sizes; (void)n_in; (void)out_size;
}

// Round 7
// 1458.050 us; speedup vs baseline: 1.1487x; 1.1487x over previous
//
#include <hip/hip_runtime.h>
#include <math.h>

#define TOK   1024
#define HSZ   1024
#define DIM   128
#define NWRDC 32000
#define NTGTC 2000

typedef __attribute__((ext_vector_type(8))) short bf16x8;
typedef __attribute__((ext_vector_type(4))) float f32x4;

__device__ __forceinline__ ushort f2bf(float x) {
    union { float f; uint u; } c; c.f = x;
    return (ushort)((c.u + 0x7fffu + ((c.u >> 16) & 1u)) >> 16);
}
__device__ __forceinline__ float bf2f(ushort h) {
    union { uint u; float f; } c; c.u = ((uint)h) << 16;
    return c.f;
}
__device__ __forceinline__ uint4 pk8(const ushort v[8]) {
    uint4 u;
    u.x = (uint)v[0] | ((uint)v[1] << 16);
    u.y = (uint)v[2] | ((uint)v[3] << 16);
    u.z = (uint)v[4] | ((uint)v[5] << 16);
    u.w = (uint)v[6] | ((uint)v[7] << 16);
    return u;
}
// sorted top-3 insert, ties -> smaller index wins
__device__ __forceinline__ void ins3(float v, int ix, float s[3], int ii[3]) {
    if (v > s[0] || (v == s[0] && ix < ii[0])) {
        s[2] = s[1]; ii[2] = ii[1]; s[1] = s[0]; ii[1] = ii[0]; s[0] = v; ii[0] = ix;
    } else if (v > s[1] || (v == s[1] && ix < ii[1])) {
        s[2] = s[1]; ii[2] = ii[1]; s[1] = v; ii[1] = ix;
    } else if (v > s[2] || (v == s[2] && ix < ii[2])) {
        s[2] = v; ii[2] = ix;
    }
}

#define GLL16(SRC, DST) __builtin_amdgcn_global_load_lds( \
    (const __attribute__((address_space(1))) void*)(SRC), \
    (__attribute__((address_space(3))) void*)(DST), 16, 0, 0)

// ---------------------------------------------------------------------------
// split ctx into 3 bf16 terms (heads use hi; cpy uses all 3)
// ---------------------------------------------------------------------------
__global__ __launch_bounds__(256) void split_ctx3(
    const float* __restrict__ x, ushort* __restrict__ hp,
    ushort* __restrict__ mp, ushort* __restrict__ lp)
{
    const int i4 = (blockIdx.x * 256 + threadIdx.x) * 4;
    float4 v = *(const float4*)(x + i4);
    float xs[4] = {v.x, v.y, v.z, v.w};
    ushort hh[4], mm[4], ll[4];
    #pragma unroll
    for (int k = 0; k < 4; ++k) {
        ushort h = f2bf(xs[k]);
        float r1 = xs[k] - bf2f(h);
        ushort m = f2bf(r1);
        ushort l = f2bf(r1 - bf2f(m));
        hh[k] = h; mm[k] = m; ll[k] = l;
    }
    uint2 u;
    u.x = (uint)hh[0] | ((uint)hh[1] << 16); u.y = (uint)hh[2] | ((uint)hh[3] << 16);
    *(uint2*)(hp + i4) = u;
    u.x = (uint)mm[0] | ((uint)mm[1] << 16); u.y = (uint)mm[2] | ((uint)mm[3] << 16);
    *(uint2*)(mp + i4) = u;
    u.x = (uint)ll[0] | ((uint)ll[1] << 16); u.y = (uint)ll[2] | ((uint)ll[3] << 16);
    *(uint2*)(lp + i4) = u;
}

// ---------------------------------------------------------------------------
// head body: single-pass bf16 logits GEMM. A via gll (dbuf, swizzled via
// pre-XOR'd source -- r6-verified). B: coalesced f32 reg loads issued at step
// start, RNE-bf16 convert + swizzled ds_write at step end (r4-verified
// latency-hiding pattern). 16 MFMA/step, one barrier/step. Epilogue: r6's
// exp/sum/top-3 + P@emb (verified).
// LDS (bytes): A0@0 A1@8192 B0@16384 B1@24576 (staging 32KB)
//   epilogue alias: P@0 [128][136]us, EM@34816 [128][72]us (ends 53248)
//   stats: wsum@53248 bval@54272 bidx@57344 -> 60416
// element (row,k): pair=row>>1, ch=(((row&1)<<2)|(k>>3))^(pair&7)^((pair>>3)&3)
//   byte = pair*128 + ch*16 + (k&7)*2
// ---------------------------------------------------------------------------
__device__ __forceinline__ void head_body(
    char* smem, int b, int NVx,
    const ushort* __restrict__ ctx_hi, const float* __restrict__ W,
    const float* __restrict__ bias, const float* __restrict__ g,
    const float* __restrict__ emb,
    int V, int ldg, int n_tiles,
    float* __restrict__ wsW, float* __restrict__ wsBV,
    int* __restrict__ wsBI, float* __restrict__ wsE)
{
    ushort* Pl = (ushort*)smem;
    ushort* EM = (ushort*)(smem + 34816);
    float* sm_wsum = (float*)(smem + 53248);
    float* sm_bval = (float*)(smem + 54272);
    int*   sm_bidx = (int*)(smem + 57344);

    const int tid  = threadIdx.x;
    const int lane = tid & 63;
    const int fr   = lane & 15;
    const int fg   = lane >> 4;
    const int wv   = tid >> 6;
    const int wrow = wv >> 1;
    const int wcol = wv & 1;
    const int split = b % NVx;
    const int t0    = (b / NVx) * 128;

    if (tid < 128) {
        sm_wsum[tid * 2] = 0.f; sm_wsum[tid * 2 + 1] = 0.f;
        #pragma unroll
        for (int s = 0; s < 3; ++s) {
            sm_bval[(tid * 2) * 3 + s] = -INFINITY;
            sm_bval[(tid * 2 + 1) * 3 + s] = -INFINITY;
            sm_bidx[(tid * 2) * 3 + s] = 0;
            sm_bidx[(tid * 2 + 1) * 3 + s] = 0;
        }
    }

    // fragment read offsets (r6-verified)
    const int chunkRd0 = (((fr & 1) << 2) | fg) ^ ((fr >> 1) & 7);
    int aRd[4], bRd[4];
    #pragma unroll
    for (int i = 0; i < 4; ++i) {
        aRd[i] = wrow * 4096 + i * 1024 + (fr >> 1) * 128 + ((chunkRd0 ^ i) << 4);
        bRd[i] = wcol * 4096 + i * 1024 + (fr >> 1) * 128 + ((chunkRd0 ^ i) << 4);
    }

    // A gll lane constants (r6-verified)
    const int v_ = (lane & 7) ^ (lane >> 3) ^ (wv & 3);
    int rowq[2];
    #pragma unroll
    for (int q = 0; q < 2; ++q)
        rowq[q] = 2 * (q * 32 + wv * 8 + (lane >> 3)) + (v_ >> 2);
    const int glK = (v_ & 3) * 8;
    const size_t srcA0 = (size_t)(t0 + rowq[0]) * HSZ + glK;
    const size_t srcA1 = (size_t)(t0 + rowq[1]) * HSZ + glK;
    const int dA0 = wv * 1024, dA1 = 4096 + wv * 1024;

    // W staging: thread covers cols c4..c4+3, k rows {hb2,hb2+1,hb2+16,hb2+17}
    const int c4 = (tid & 31) * 4;
    const int hb2 = (tid >> 5) * 2;
    int wb01[4], wb23[4];
    #pragma unroll
    for (int i = 0; i < 4; ++i) {
        const int col = c4 + i;
        const int pair = col >> 1;
        const int ch01 = (((col & 1) << 2) | (hb2 >> 3)) ^ (pair & 7) ^ ((pair >> 3) & 3);
        const int ch23 = (((col & 1) << 2) | (2 + (hb2 >> 3))) ^ (pair & 7) ^ ((pair >> 3) & 3);
        wb01[i] = pair * 128 + ch01 * 16 + (hb2 & 7) * 2;
        wb23[i] = pair * 128 + ch23 * 16 + (hb2 & 7) * 2;
    }

    f32x4 zero4 = {0.f, 0.f, 0.f, 0.f};
    f32x4 Eacc[4][4];
    #pragma unroll
    for (int i = 0; i < 4; ++i)
        #pragma unroll
        for (int j = 0; j < 4; ++j) Eacc[i][j] = zero4;

    const int tbeg = (split * n_tiles) / NVx;
    const int tend = ((split + 1) * n_tiles) / NVx;

    #define STAGE_A(STEP, BASE) do {                                    \
        GLL16(ctx_hi + srcA0 + (size_t)(STEP) * 32, (BASE) + dA0);      \
        GLL16(ctx_hi + srcA1 + (size_t)(STEP) * 32, (BASE) + dA1);      \
    } while (0)

    #define LOAD_W(STEP, VV) do {                                        \
        const int gc_ = c0 + c4;                                         \
        if (gc_ + 3 < V) {                                               \
            const float* p_ = W + (size_t)((STEP) * 32 + hb2) * V + gc_; \
            VV[0] = *(const float4*)p_;                                  \
            VV[1] = *(const float4*)(p_ + V);                            \
            VV[2] = *(const float4*)(p_ + 16 * (size_t)V);               \
            VV[3] = *(const float4*)(p_ + 17 * (size_t)V);               \
        } else {                                                         \
            float4 z_ = {0.f, 0.f, 0.f, 0.f};                            \
            VV[0] = z_; VV[1] = z_; VV[2] = z_; VV[3] = z_;              \
        }                                                                \
    } while (0)

    #define CONV_W(BB, VV) do {                                          \
        _Pragma("unroll")                                                \
        for (int i_ = 0; i_ < 4; ++i_) {                                 \
            ushort h0b = f2bf(((const float*)&VV[0])[i_]);               \
            ushort h1b = f2bf(((const float*)&VV[1])[i_]);               \
            ushort h2b = f2bf(((const float*)&VV[2])[i_]);               \
            ushort h3b = f2bf(((const float*)&VV[3])[i_]);               \
            *(uint*)((BB) + wb01[i_]) = (uint)h0b | ((uint)h1b << 16);   \
            *(uint*)((BB) + wb23[i_]) = (uint)h2b | ((uint)h3b << 16);   \
        }                                                                \
    } while (0)

    for (int tt = tbeg; tt < tend; ++tt) {
        const int c0 = tt * 128;
        f32x4 acc[4][4];
        #pragma unroll
        for (int i = 0; i < 4; ++i)
            #pragma unroll
            for (int j = 0; j < 4; ++j) acc[i][j] = zero4;

        // prologue: stage step 0
        STAGE_A(0, smem);
        {
            float4 v0[4];
            LOAD_W(0, v0);
            CONV_W(smem + 16384, v0);
        }
        __syncthreads();

        for (int ks = 0; ks < 32; ++ks) {
            const int cur = ks & 1;
            const bool more = (ks + 1) < 32;
            float4 vn[4];
            if (more) {
                STAGE_A(ks + 1, smem + (cur ^ 1) * 8192);
                LOAD_W(ks + 1, vn);
            }
            const char* bA = smem + cur * 8192;
            const char* bB = smem + 16384 + cur * 8192;
            bf16x8 ah[4], bh[4];
            #pragma unroll
            for (int i = 0; i < 4; ++i) ah[i] = *(const bf16x8*)(bA + aRd[i]);
            #pragma unroll
            for (int j = 0; j < 4; ++j) bh[j] = *(const bf16x8*)(bB + bRd[j]);
            __builtin_amdgcn_s_setprio(1);
            #pragma unroll
            for (int j = 0; j < 4; ++j)
                #pragma unroll
                for (int i = 0; i < 4; ++i)
                    acc[i][j] = __builtin_amdgcn_mfma_f32_16x16x32_bf16(ah[i], bh[j], acc[i][j], 0, 0, 0);
            __builtin_amdgcn_s_setprio(0);
            if (more) CONV_W(smem + 16384 + (cur ^ 1) * 8192, vn);
            __syncthreads();
        }

        // ---- epilogue: bias + gumbel + exp, P -> LDS, Z + top-3 stats ----
        float bias4[4];
        #pragma unroll
        for (int j = 0; j < 4; ++j) {
            const int gc = c0 + wcol * 64 + j * 16 + fr;
            bias4[j] = (gc < V) ? bias[gc] : 0.f;
        }
        #pragma unroll
        for (int i = 0; i < 4; ++i) {
            #pragma unroll
            for (int r = 0; r < 4; ++r) {
                const int trow = wrow * 64 + i * 16 + fg * 4 + r;
                const float* gp = g + (size_t)(t0 + trow) * ldg + c0 + wcol * 64 + fr;
                float esum = 0.f;
                float t3v[3] = {-INFINITY, -INFINITY, -INFINITY};
                int   t3i[3] = {0, 0, 0};
                #pragma unroll
                for (int j = 0; j < 4; ++j) {
                    const int gc = c0 + wcol * 64 + j * 16 + fr;
                    float e = 0.f;
                    if (gc < V) {
                        const float s = acc[i][j][r] + bias4[j] + gp[j * 16];
                        e = __expf(s);
                        esum += e;
                        ins3(s, gc, t3v, t3i);
                    }
                    Pl[trow * 136 + wcol * 64 + j * 16 + fr] = f2bf(e);
                }
                #pragma unroll
                for (int off = 1; off < 16; off <<= 1) {
                    float o0 = __shfl_xor(t3v[0], off, 64);
                    float o1 = __shfl_xor(t3v[1], off, 64);
                    float o2 = __shfl_xor(t3v[2], off, 64);
                    int q0 = __shfl_xor(t3i[0], off, 64);
                    int q1 = __shfl_xor(t3i[1], off, 64);
                    int q2 = __shfl_xor(t3i[2], off, 64);
                    esum += __shfl_xor(esum, off, 64);
                    ins3(o0, q0, t3v, t3i);
                    ins3(o1, q1, t3v, t3i);
                    ins3(o2, q2, t3v, t3i);
                }
                if (fr == 0) {
                    const int sb = (trow * 2 + wcol) * 3;
                    sm_wsum[trow * 2 + wcol] += esum;
                    float sh[3] = {sm_bval[sb], sm_bval[sb + 1], sm_bval[sb + 2]};
                    int shi[3] = {sm_bidx[sb], sm_bidx[sb + 1], sm_bidx[sb + 2]};
                    ins3(t3v[0], t3i[0], sh, shi);
                    ins3(t3v[1], t3i[1], sh, shi);
                    ins3(t3v[2], t3i[2], sh, shi);
                    sm_bval[sb] = sh[0]; sm_bval[sb + 1] = sh[1]; sm_bval[sb + 2] = sh[2];
                    sm_bidx[sb] = shi[0]; sm_bidx[sb + 1] = shi[1]; sm_bidx[sb + 2] = shi[2];
                }
            }
        }

        // ---- E-GEMM in two 64-col halves ----
        #pragma unroll
        for (int hf = 0; hf < 2; ++hf) {
            __syncthreads();
            #pragma unroll
            for (int rr = 0; rr < 4; ++rr) {
                const int task = tid + rr * 256;
                const int dd0 = task & 127;
                const int cc = task >> 7;
                ushort o8[8];
                #pragma unroll
                for (int j = 0; j < 8; ++j) {
                    const int gc = c0 + hf * 64 + cc * 8 + j;
                    o8[j] = (gc < V) ? f2bf(emb[(size_t)gc * DIM + dd0]) : (ushort)0;
                }
                *(uint4*)(EM + dd0 * 72 + cc * 8) = pk8(o8);
            }
            __syncthreads();
            #pragma unroll
            for (int ksb = 0; ksb < 2; ++ksb) {
                bf16x8 ap[4];
                #pragma unroll
                for (int i = 0; i < 4; ++i) {
                    const int row = wrow * 64 + i * 16 + fr;
                    ap[i] = *(const bf16x8*)(Pl + row * 136 + hf * 64 + ksb * 32 + fg * 8);
                }
                #pragma unroll
                for (int j = 0; j < 4; ++j) {
                    const int dd = wcol * 64 + j * 16 + fr;
                    bf16x8 eb = *(const bf16x8*)(EM + dd * 72 + ksb * 32 + fg * 8);
                    #pragma unroll
                    for (int i = 0; i < 4; ++i)
                        Eacc[i][j] = __builtin_amdgcn_mfma_f32_16x16x32_bf16(ap[i], eb, Eacc[i][j], 0, 0, 0);
                }
            }
        }
        __syncthreads();
    }

    __syncthreads();
    if (tid < 128) {
        const int sb0 = (tid * 2) * 3, sb1 = (tid * 2 + 1) * 3;
        float v3[3] = {sm_bval[sb0], sm_bval[sb0 + 1], sm_bval[sb0 + 2]};
        int i3[3] = {sm_bidx[sb0], sm_bidx[sb0 + 1], sm_bidx[sb0 + 2]};
        ins3(sm_bval[sb1], sm_bidx[sb1], v3, i3);
        ins3(sm_bval[sb1 + 1], sm_bidx[sb1 + 1], v3, i3);
        ins3(sm_bval[sb1 + 2], sm_bidx[sb1 + 2], v3, i3);
        const size_t o = (size_t)split * TOK + t0 + tid;
        wsW[o] = sm_wsum[tid * 2] + sm_wsum[tid * 2 + 1];
        #pragma unroll
        for (int s = 0; s < 3; ++s) { wsBV[o * 3 + s] = v3[s]; wsBI[o * 3 + s] = i3[s]; }
    }
    #pragma unroll
    for (int i = 0; i < 4; ++i)
        #pragma unroll
        for (int j = 0; j < 4; ++j)
            #pragma unroll
            for (int r = 0; r < 4; ++r) {
                const int trow = wrow * 64 + i * 16 + fg * 4 + r;
                const int dd   = wcol * 64 + j * 16 + fr;
                wsE[((size_t)split * TOK + t0 + trow) * DIM + dd] = Eacc[i][j][r];
            }
    #undef STAGE_A
    #undef LOAD_W
    #undef CONV_W
}

// ---------------------------------------------------------------------------
// cpy body (r5-verified): C-tile = ctx @ W_cpy (3-term, 6 passes) with fused
// partial pcpy dot -> pcpyP[colsplit][t]
// ---------------------------------------------------------------------------
__device__ __forceinline__ void cpy_body(
    char* smemc, int cb,
    const ushort* __restrict__ ahi, const ushort* __restrict__ amd,
    const ushort* __restrict__ alo, const float* __restrict__ Wc,
    const float* __restrict__ ctx, const float* __restrict__ bc,
    float* __restrict__ pcpyP)
{
    ushort* sm = (ushort*)smemc;
    ushort* Ah = sm;
    ushort* Am = sm + 5120;
    ushort* Al = sm + 10240;
    ushort* Bh = sm + 15360;
    ushort* Bm = sm + 20480;
    ushort* Bl = sm + 25600;

    const int tid  = threadIdx.x;
    const int lane = tid & 63;
    const int fr   = lane & 15;
    const int fg   = lane >> 4;
    const int w    = tid >> 6;
    const int wrow = w >> 1;
    const int wcol = w & 1;
    const int t0   = (cb >> 3) * 128;
    const int c0   = (cb & 7) * 128;

    const int arow = tid >> 2, akc = tid & 3;
    const int bcol = tid & 127, bkc0 = tid >> 7;

    f32x4 zero4 = {0.f, 0.f, 0.f, 0.f};
    f32x4 acc[4][4];
    #pragma unroll
    for (int i = 0; i < 4; ++i)
        #pragma unroll
        for (int j = 0; j < 4; ++j) acc[i][j] = zero4;

    for (int h0 = 0; h0 < HSZ; h0 += 32) {
        uint4 aH[2], aM[2], aL[2];
        float bx[2][8];
        #pragma unroll
        for (int rr = 0; rr < 2; ++rr) {
            const size_t so = (size_t)(t0 + arow + rr * 64) * HSZ + h0 + akc * 8;
            aH[rr] = *(const uint4*)(ahi + so);
            aM[rr] = *(const uint4*)(amd + so);
            aL[rr] = *(const uint4*)(alo + so);
        }
        #pragma unroll
        for (int rr = 0; rr < 2; ++rr) {
            const int kc = bkc0 + rr * 2;
            const float* wp = Wc + (size_t)(h0 + kc * 8) * HSZ + c0 + bcol;
            #pragma unroll
            for (int j = 0; j < 8; ++j) bx[rr][j] = wp[(size_t)j * HSZ];
        }
        __syncthreads();
        #pragma unroll
        for (int rr = 0; rr < 2; ++rr) {
            const int row = arow + rr * 64;
            *(uint4*)(Ah + row * 40 + akc * 8) = aH[rr];
            *(uint4*)(Am + row * 40 + akc * 8) = aM[rr];
            *(uint4*)(Al + row * 40 + akc * 8) = aL[rr];
        }
        #pragma unroll
        for (int rr = 0; rr < 2; ++rr) {
            const int kc = bkc0 + rr * 2;
            ushort hh[8], mm[8], ll[8];
            #pragma unroll
            for (int j = 0; j < 8; ++j) {
                float x = bx[rr][j];
                ushort h = f2bf(x);
                float r1 = x - bf2f(h);
                ushort m = f2bf(r1);
                hh[j] = h; mm[j] = m; ll[j] = f2bf(r1 - bf2f(m));
            }
            *(uint4*)(Bh + bcol * 40 + kc * 8) = pk8(hh);
            *(uint4*)(Bm + bcol * 40 + kc * 8) = pk8(mm);
            *(uint4*)(Bl + bcol * 40 + kc * 8) = pk8(ll);
        }
        __syncthreads();
        bf16x8 a1[4], a2[4], a3[4];
        #pragma unroll
        for (int i = 0; i < 4; ++i) {
            const int row = wrow * 64 + i * 16 + fr;
            a1[i] = *(const bf16x8*)(Ah + row * 40 + fg * 8);
            a2[i] = *(const bf16x8*)(Am + row * 40 + fg * 8);
            a3[i] = *(const bf16x8*)(Al + row * 40 + fg * 8);
        }
        #pragma unroll
        for (int j = 0; j < 4; ++j) {
            const int cr = wcol * 64 + j * 16 + fr;
            bf16x8 b1 = *(const bf16x8*)(Bh + cr * 40 + fg * 8);
            bf16x8 b2 = *(const bf16x8*)(Bm + cr * 40 + fg * 8);
            bf16x8 b3 = *(const bf16x8*)(Bl + cr * 40 + fg * 8);
            #pragma unroll
            for (int i = 0; i < 4; ++i) {
                acc[i][j] = __builtin_amdgcn_mfma_f32_16x16x32_bf16(a1[i], b1, acc[i][j], 0, 0, 0);
                acc[i][j] = __builtin_amdgcn_mfma_f32_16x16x32_bf16(a1[i], b2, acc[i][j], 0, 0, 0);
                acc[i][j] = __builtin_amdgcn_mfma_f32_16x16x32_bf16(a2[i], b1, acc[i][j], 0, 0, 0);
                acc[i][j] = __builtin_amdgcn_mfma_f32_16x16x32_bf16(a1[i], b3, acc[i][j], 0, 0, 0);
                acc[i][j] = __builtin_amdgcn_mfma_f32_16x16x32_bf16(a3[i], b1, acc[i][j], 0, 0, 0);
                acc[i][j] = __builtin_amdgcn_mfma_f32_16x16x32_bf16(a2[i], b2, acc[i][j], 0, 0, 0);
            }
        }
    }

    __syncthreads();
    float* red = (float*)smemc;
    float bb[4];
    #pragma unroll
    for (int j = 0; j < 4; ++j) bb[j] = bc[c0 + wcol * 64 + j * 16 + fr];
    #pragma unroll
    for (int i = 0; i < 4; ++i) {
        #pragma unroll
        for (int r = 0; r < 4; ++r) {
            const int trow = wrow * 64 + i * 16 + fg * 4 + r;
            const float* cx = ctx + (size_t)(t0 + trow) * HSZ + c0;
            float s = 0.f;
            #pragma unroll
            for (int j = 0; j < 4; ++j) {
                const int dd = wcol * 64 + j * 16 + fr;
                s += (acc[i][j][r] + bb[j]) * cx[dd];
            }
            #pragma unroll
            for (int off = 1; off < 16; off <<= 1) s += __shfl_xor(s, off, 64);
            if (fr == 0) red[trow * 2 + wcol] = s;
        }
    }
    __syncthreads();
    if (tid < 128)
        pcpyP[(size_t)(cb & 7) * TOK + t0 + tid] = red[tid * 2] + red[tid * 2 + 1];
}

// ---------------------------------------------------------------------------
__global__ __launch_bounds__(256, 2) void mega_kernel(
    const ushort* __restrict__ ctxh, const ushort* __restrict__ ctxm,
    const ushort* __restrict__ ctxl,
    const float* __restrict__ W_nrm, const float* __restrict__ b_nrm,
    const float* __restrict__ g_nrm, const float* __restrict__ word_emb,
    const float* __restrict__ W_spt, const float* __restrict__ b_spt,
    const float* __restrict__ g_spt, const float* __restrict__ word_emb_tgt,
    const float* __restrict__ W_cpy, const float* __restrict__ b_cpy,
    const float* __restrict__ ctx, float* __restrict__ pcpyP,
    int NVn, int NVs,
    float* __restrict__ nW, float* __restrict__ nBV, int* __restrict__ nBI,
    float* __restrict__ nE,
    float* __restrict__ sW, float* __restrict__ sBV, int* __restrict__ sBI,
    float* __restrict__ sE)
{
    __shared__ __align__(16) char smem[61440];
    const int bid = (int)blockIdx.x;
    if (bid < 64) {
        cpy_body(smem, bid, ctxh, ctxm, ctxl, W_cpy, ctx, b_cpy, pcpyP);
    } else if (bid < 64 + NVn * 8) {
        head_body(smem, bid - 64, NVn, ctxh, W_nrm, b_nrm, g_nrm, word_emb,
                  NWRDC, NWRDC + 1, 250, nW, nBV, nBI, nE);
    } else {
        head_body(smem, bid - 64 - NVn * 8, NVs, ctxh, W_spt, b_spt, g_spt,
                  word_emb_tgt, NTGTC, NTGTC, 16, sW, sBV, sBI, sE);
    }
}

// ---------------------------------------------------------------------------
// combine2: merge partials; conditional exact (f64) recompute of top-3
// candidates when the approximate gap is within the single-pass error bound.
// ---------------------------------------------------------------------------
__global__ __launch_bounds__(128) void combine2(
    const int* __restrict__ inp_word, const float* __restrict__ masks,
    const int* __restrict__ spt_mask, const int* __restrict__ tgt_ids,
    const float* __restrict__ word_emb, const float* __restrict__ pcpyP,
    const float* __restrict__ g_nrm, const float* __restrict__ g_spt,
    const float* __restrict__ ctx,
    const float* __restrict__ b_nrm, const float* __restrict__ b_spt,
    const float* __restrict__ W_nrm, const float* __restrict__ W_spt,
    const float* __restrict__ nW, const float* __restrict__ nBV,
    const int* __restrict__ nBI, const float* __restrict__ nE, int NVn,
    const float* __restrict__ sW, const float* __restrict__ sBV,
    const int* __restrict__ sBI, const float* __restrict__ sE, int NVs,
    float* __restrict__ out)
{
    __shared__ double sredN[2][3];
    __shared__ double sredS[2][3];
    const int t = (int)blockIdx.x;
    const int d = (int)threadIdx.x;

    float Wn = 0.f, En = 0.f;
    float cv[3] = {-INFINITY, -INFINITY, -INFINITY}; int ci[3] = {0, 0, 0};
    for (int v = 0; v < NVn; ++v) {
        const size_t o = (size_t)v * TOK + t;
        Wn += nW[o];
        En += nE[o * DIM + d];
        #pragma unroll
        for (int s = 0; s < 3; ++s) ins3(nBV[o * 3 + s], nBI[o * 3 + s], cv, ci);
    }
    float Ws = 0.f, Es = 0.f;
    float dv[3] = {-INFINITY, -INFINITY, -INFINITY}; int di[3] = {0, 0, 0};
    for (int v = 0; v < NVs; ++v) {
        const size_t o = (size_t)v * TOK + t;
        Ws += sW[o];
        Es += sE[o * DIM + d];
        #pragma unroll
        for (int s = 0; s < 3; ++s) ins3(sBV[o * 3 + s], sBI[o * 3 + s], dv, di);
    }

    float pc = 0.f;
    #pragma unroll
    for (int y = 0; y < 8; ++y) pc += pcpyP[(size_t)y * TOK + t];
    const int iw = inp_word[t];
    const float sc = pc + g_nrm[(size_t)t * (NWRDC + 1) + NWRDC];

    const float EPS = 0.02f;
    const bool needN = (cv[0] - cv[1] <= EPS) || (fabsf(sc - cv[0]) <= EPS);
    const bool needS = (dv[0] - dv[1] <= EPS);

    if (needN || needS) {
        float cxv[8];
        #pragma unroll
        for (int q = 0; q < 8; ++q) cxv[q] = ctx[(size_t)t * HSZ + d * 8 + q];
        #pragma unroll
        for (int c = 0; c < 3; ++c) {
            double p = 0.0;
            if (needN && cv[c] > -1e30f) {
                const float* wc = W_nrm + ci[c];
                #pragma unroll
                for (int q = 0; q < 8; ++q)
                    p += (double)cxv[q] * (double)wc[(size_t)(d * 8 + q) * NWRDC];
            }
            #pragma unroll
            for (int off = 32; off > 0; off >>= 1) p += __shfl_down(p, off, 64);
            if ((d & 63) == 0) sredN[d >> 6][c] = p;
        }
        #pragma unroll
        for (int c = 0; c < 3; ++c) {
            double p = 0.0;
            if (needS && dv[c] > -1e30f) {
                const float* wc = W_spt + di[c];
                #pragma unroll
                for (int q = 0; q < 8; ++q)
                    p += (double)cxv[q] * (double)wc[(size_t)(d * 8 + q) * NTGTC];
            }
            #pragma unroll
            for (int off = 32; off > 0; off >>= 1) p += __shfl_down(p, off, 64);
            if ((d & 63) == 0) sredS[d >> 6][c] = p;
        }
        __syncthreads();
    }

    const float ec = __expf(sc);
    Wn += ec;
    En += ec * word_emb[(size_t)iw * DIM + d];

    const float sptf = (float)spt_mask[t];
    const float nrmf = (1.f - sptf) * masks[t];

    float eo;
    if (sptf > 0.f)      eo = Es / Ws;
    else if (nrmf > 0.f) eo = En / Wn;
    else                 eo = word_emb[(size_t)iw * DIM + d];
    out[(size_t)t * DIM + d] = eo;

    if (d == 0) {
        float bnv = cv[0]; int bni = ci[0];
        if (needN) {
            bnv = -INFINITY; bni = 0;
            #pragma unroll
            for (int c = 0; c < 3; ++c) {
                if (cv[c] > -1e30f) {
                    const float s = (float)(sredN[0][c] + sredN[1][c])
                                  + b_nrm[ci[c]]
                                  + g_nrm[(size_t)t * (NWRDC + 1) + ci[c]];
                    if (s > bnv || (s == bnv && ci[c] < bni)) { bnv = s; bni = ci[c]; }
                }
            }
        }
        float bsv = dv[0]; int bsi = di[0];
        if (needS) {
            bsv = -INFINITY; bsi = 0;
            #pragma unroll
            for (int c = 0; c < 3; ++c) {
                if (dv[c] > -1e30f) {
                    const float s = (float)(sredS[0][c] + sredS[1][c])
                                  + b_spt[di[c]]
                                  + g_spt[(size_t)t * NTGTC + di[c]];
                    if (s > bsv || (s == bsv && di[c] < bsi)) { bsv = s; bsi = di[c]; }
                }
            }
        }
        const int ynrm = (sc > bnv) ? iw : bni;
        const int yspt = tgt_ids[bsi];
        int obf;
        if (sptf > 0.f)      obf = yspt;
        else if (nrmf > 0.f) obf = ynrm;
        else                 obf = iw;
        out[(size_t)TOK * DIM + t]       = (float)obf;
        out[(size_t)TOK * DIM + TOK + t] = sptf;
    }
}

// ---------------------------------------------------------------------------
extern "C" void kernel_launch(void* const* d_in, const int* in_sizes, int n_in,
                              void* d_out, int out_size, void* d_ws, size_t ws_size,
                              hipStream_t stream)
{
    const int*   inp_word = (const int*)d_in[0];
    const float* masks    = (const float*)d_in[1];
    const int*   spt_mask = (const int*)d_in[2];
    const int*   tgt_ids  = (const int*)d_in[3];
    const float* ctx      = (const float*)d_in[4];
    const float* W_spt    = (const float*)d_in[5];
    const float* b_spt    = (const float*)d_in[6];
    const float* W_nrm    = (const float*)d_in[7];
    const float* b_nrm    = (const float*)d_in[8];
    const float* W_cpy    = (const float*)d_in[9];
    const float* b_cpy    = (const float*)d_in[10];
    const float* word_emb = (const float*)d_in[11];
    const float* word_emb_tgt = (const float*)d_in[12];
    const float* g_spt    = (const float*)d_in[13];
    const float* g_nrm    = (const float*)d_in[14];
    float* out = (float*)d_out;

    char* wsb = (char*)d_ws;
    float*  pcpyP = (float*)wsb;                             // 32 KB
    ushort* ctxh = (ushort*)(wsb + 32768);                   // 2 MB
    ushort* ctxm = ctxh + 1048576;                           // 2 MB
    ushort* ctxl = ctxm + 1048576;                           // 2 MB
    char*   region = wsb + 32768 + 6291456;
    const size_t base = 32768 + 6291456;                     // 6324224
    const size_t per_split = (size_t)TOK * (1 + 3 + 3 + DIM) * 4;  // 552960

    // tier selection: {48,8} = 512 blocks = exact 2/CU fill; NVn mult of 8
    int NVn = 1, NVs = 1;
    {
        const int tn[8] = {48, 32, 24, 16, 8, 4, 2, 1};
        const int ts[8] = { 8,  8,  8,  8, 8, 4, 2, 1};
        for (int pi = 0; pi < 8; ++pi) {
            const size_t need = base + (size_t)(tn[pi] + ts[pi]) * per_split;
            if (ws_size >= need) { NVn = tn[pi]; NVs = ts[pi]; break; }
        }
    }

    float* nW  = (float*)region;
    float* nBV = nW + (size_t)NVn * TOK;
    int*   nBI = (int*)(nBV + (size_t)NVn * TOK * 3);
    float* nE  = (float*)(nBI + (size_t)NVn * TOK * 3);
    float* sW  = nE + (size_t)NVn * TOK * DIM;
    float* sBV = sW + (size_t)NVs * TOK;
    int*   sBI = (int*)(sBV + (size_t)NVs * TOK * 3);
    float* sE  = (float*)(sBI + (size_t)NVs * TOK * 3);

    split_ctx3<<<dim3(TOK * HSZ / 1024), dim3(256), 0, stream>>>(ctx, ctxh, ctxm, ctxl);
    mega_kernel<<<dim3(64 + NVn * 8 + NVs * 8), dim3(256), 0, stream>>>(
        ctxh, ctxm, ctxl, W_nrm, b_nrm, g_nrm, word_emb,
        W_spt, b_spt, g_spt, word_emb_tgt, W_cpy, b_cpy, ctx, pcpyP,
        NVn, NVs, nW, nBV, nBI, nE, sW, sBV, sBI, sE);
    combine2<<<dim3(TOK), dim3(128), 0, stream>>>(
        inp_word, masks, spt_mask, tgt_ids, word_emb, pcpyP, g_nrm, g_spt, ctx,
        b_nrm, b_spt, W_nrm, W_spt,
        nW, nBV, nBI, nE, NVn, sW, sBV, sBI, sE, NVs, out);
    (void)in_sizes; (void)n_in; (void)out_size;
}